// Round 1
// baseline (124.145 us; speedup 1.0000x reference)
//
#include <hip/hip_runtime.h>

// Problem constants (match reference)
#define BB   8
#define CC   1024
#define TT   4096
#define HH   16
#define KK   31
#define PADD 15

#define SEG   1024              // outputs per block
#define HALO  (KK - 1)          // 30
#define TILE  (SEG + HALO)      // 1054 staged inputs

// --- softmax over the 31 taps of each of the 16 heads ---
__global__ void lwconv_softmax_w(const float* __restrict__ w, float* __restrict__ wsm) {
    int h = threadIdx.x;
    if (h < HH) {
        float buf[KK];
        float m = -1e30f;
        #pragma unroll
        for (int k = 0; k < KK; ++k) { buf[k] = w[h * KK + k]; m = fmaxf(m, buf[k]); }
        float s = 0.f;
        #pragma unroll
        for (int k = 0; k < KK; ++k) { buf[k] = expf(buf[k] - m); s += buf[k]; }
        float inv = 1.f / s;
        #pragma unroll
        for (int k = 0; k < KK; ++k) wsm[h * KK + k] = buf[k] * inv;
    }
}

// --- main depthwise conv: one block = one 1024-wide segment of one row ---
__global__ __launch_bounds__(256) void lwconv_main(const float* __restrict__ inp,
                                                   const float* __restrict__ wsm,
                                                   const float* __restrict__ bias,
                                                   float* __restrict__ out) {
    __shared__ float s[TILE];
    __shared__ float sw[KK];

    const int blk  = blockIdx.x;
    const int seg  = blk & 3;            // 4 segments per row (T/SEG)
    const int row  = blk >> 2;           // row = b*C + ch, 0..8191
    const int ch   = row & (CC - 1);     // C = 1024 (pow2)
    const int head = ch >> 6;            // 64 channels per head
    const int tid  = threadIdx.x;

    if (tid < KK) sw[tid] = wsm[head * KK + tid];

    const float* rowp = inp + (size_t)row * TT;
    const int base = seg * SEG - PADD;

    #pragma unroll
    for (int it = 0; it < (TILE + 255) / 256; ++it) {
        int i = tid + it * 256;
        if (i < TILE) {
            int t = base + i;
            s[i] = (t >= 0 && t < TT) ? rowp[t] : 0.f;
        }
    }
    __syncthreads();

    const float bval = bias[head];
    float* orow = out + (size_t)row * TT + seg * SEG;

    #pragma unroll
    for (int m = 0; m < 4; ++m) {
        const int j = tid + m * 256;     // output offset within segment
        float acc = bval;
        #pragma unroll
        for (int k = 0; k < KK; ++k) {
            acc = fmaf(s[j + k], sw[k], acc);
        }
        orow[j] = acc;
    }
}

extern "C" void kernel_launch(void* const* d_in, const int* in_sizes, int n_in,
                              void* d_out, int out_size, void* d_ws, size_t ws_size,
                              hipStream_t stream) {
    const float* inp    = (const float*)d_in[0];   // (B, C, T) fp32
    const float* weight = (const float*)d_in[1];   // (H, 1, K) fp32
    const float* bias   = (const float*)d_in[2];   // (H,) fp32
    float* out = (float*)d_out;
    float* wsm = (float*)d_ws;                     // H*K softmaxed weights

    lwconv_softmax_w<<<1, 64, 0, stream>>>(weight, wsm);

    const int rows = BB * CC;                      // 8192
    const int segs = TT / SEG;                     // 4
    lwconv_main<<<rows * segs, 256, 0, stream>>>(inp, wsm, bias, out);
}

// Round 2
// 88.857 us; speedup vs baseline: 1.3971x; 1.3971x over previous
//
#include <hip/hip_runtime.h>

// Problem constants (match reference)
#define BB   8
#define CC   1024
#define TT   4096
#define HH   16
#define KK   31
#define PADD 15

#define RPT  16                 // outputs per thread
#define WIN  48                 // input window floats per thread (aligned)

// --- softmax over the 31 taps of each of the 16 heads ---
__global__ void lwconv_softmax_w(const float* __restrict__ w, float* __restrict__ wsm) {
    int h = threadIdx.x;
    if (h < HH) {
        float buf[KK];
        float m = -1e30f;
        #pragma unroll
        for (int k = 0; k < KK; ++k) { buf[k] = w[h * KK + k]; m = fmaxf(m, buf[k]); }
        float s = 0.f;
        #pragma unroll
        for (int k = 0; k < KK; ++k) { buf[k] = expf(buf[k] - m); s += buf[k]; }
        float inv = 1.f / s;
        #pragma unroll
        for (int k = 0; k < KK; ++k) wsm[h * KK + k] = buf[k] * inv;
    }
}

// --- main depthwise conv: one block = one row (b,c); thread = 16 consecutive t ---
// out[t] = bias + sum_k w[k] * x[t + k - 15]
// Thread window: xv[e] = x[a - 16 + e], e in [0,48);  out[a+r] uses xv[r+1+k].
__global__ __launch_bounds__(256) void lwconv_main(const float* __restrict__ inp,
                                                   const float* __restrict__ wsm,
                                                   const float* __restrict__ bias,
                                                   float* __restrict__ out) {
    const int row  = blockIdx.x;         // b*C + ch, 0..8191
    const int ch   = row & (CC - 1);
    const int head = ch >> 6;            // 64 channels per head
    const int tid  = threadIdx.x;
    const int a    = tid << 4;           // first output index of this thread

    // block-uniform weights -> scalar regs
    float w[KK];
    #pragma unroll
    for (int k = 0; k < KK; ++k) w[k] = wsm[head * KK + k];
    const float bval = bias[head];

    const float* rowp = inp + (size_t)row * TT;

    float xv[WIN];
    #pragma unroll
    for (int c = 0; c < WIN / 4; ++c) {
        const int ge = a - 16 + 4 * c;   // global element index of chunk start
        float4 v;
        if (ge >= 0 && ge <= TT - 4)
            v = *reinterpret_cast<const float4*>(rowp + ge);
        else
            v = make_float4(0.f, 0.f, 0.f, 0.f);   // whole chunk is padding
        xv[4 * c + 0] = v.x; xv[4 * c + 1] = v.y;
        xv[4 * c + 2] = v.z; xv[4 * c + 3] = v.w;
    }

    float acc[RPT];
    #pragma unroll
    for (int r = 0; r < RPT; ++r) acc[r] = bval;

    #pragma unroll
    for (int k = 0; k < KK; ++k) {
        #pragma unroll
        for (int r = 0; r < RPT; ++r) {
            acc[r] = fmaf(xv[r + 1 + k], w[k], acc[r]);
        }
    }

    float* orow = out + (size_t)row * TT + a;
    #pragma unroll
    for (int c = 0; c < RPT / 4; ++c) {
        *reinterpret_cast<float4*>(orow + 4 * c) =
            make_float4(acc[4 * c], acc[4 * c + 1], acc[4 * c + 2], acc[4 * c + 3]);
    }
}

extern "C" void kernel_launch(void* const* d_in, const int* in_sizes, int n_in,
                              void* d_out, int out_size, void* d_ws, size_t ws_size,
                              hipStream_t stream) {
    const float* inp    = (const float*)d_in[0];   // (B, C, T) fp32
    const float* weight = (const float*)d_in[1];   // (H, 1, K) fp32
    const float* bias   = (const float*)d_in[2];   // (H,) fp32
    float* out = (float*)d_out;
    float* wsm = (float*)d_ws;                     // H*K softmaxed weights

    lwconv_softmax_w<<<1, 64, 0, stream>>>(weight, wsm);

    const int rows = BB * CC;                      // 8192 = one block per row
    lwconv_main<<<rows, 256, 0, stream>>>(inp, wsm, bias, out);
}